// Round 7
// baseline (920.497 us; speedup 1.0000x reference)
//
#include <hip/hip_runtime.h>

#define H  512
#define NN 10000
#define SS 20
#define VV 100000
#define EE 100000

typedef __bf16 bf16x8 __attribute__((ext_vector_type(8)));
typedef float  f32x4  __attribute__((ext_vector_type(4)));

__device__ __forceinline__ unsigned short f2bf(float f) {
  unsigned u = __builtin_bit_cast(unsigned, f);
  u += 0x7FFFu + ((u >> 16) & 1u);
  return (unsigned short)(u >> 16);
}
__device__ __forceinline__ float bflo(int x) {
  return __builtin_bit_cast(float, (unsigned)x << 16);
}
__device__ __forceinline__ float bfhi(int x) {
  return __builtin_bit_cast(float, (unsigned)x & 0xFFFF0000u);
}
__device__ __forceinline__ float sigm(float x) { return 1.f / (1.f + __expf(-x)); }

// pack two f32 -> two bf16 in one dword: round-half-up (+0x8000) + v_perm_b32.
__device__ __forceinline__ unsigned pk(float lo, float hi) {
  unsigned a = __builtin_bit_cast(unsigned, lo) + 0x8000u;
  unsigned b = __builtin_bit_cast(unsigned, hi) + 0x8000u;
  return __builtin_amdgcn_perm(b, a, 0x07060302u);
}
__device__ __forceinline__ void cvt_store8(unsigned short* dst, float4 a, float4 b) {
  int4 v;
  v.x = (int)pk(a.x, a.y); v.y = (int)pk(a.z, a.w);
  v.z = (int)pk(b.x, b.y); v.w = (int)pk(b.z, b.w);
  *(int4*)dst = v;
}
__device__ __forceinline__ bf16x8 cvt8(float4 a, float4 b) {
  int4 v;
  v.x = (int)pk(a.x, a.y); v.y = (int)pk(a.z, a.w);
  v.z = (int)pk(b.x, b.y); v.w = (int)pk(b.z, b.w);
  return __builtin_bit_cast(bf16x8, v);
}

// ---------------- fused gather + GEMM + GRU scan (persistent-B, 8 waves) ----
// grid (8 cgroups of 64 ch, 128 node-splits), block 512 = 8 waves.
// Wave w owns 32 cols (2 N-tiles): tile t col -> panel pp=r&3 (r0,z0,r1,z1),
// channel c0+8w+(r>>2)+4t. B (full K=512) persists in 128 VGPRs/lane.
// A-tile (80 rows x 64 k) is shared by all 8 waves -> emb gather passes,
// conversion VALU and staging LDS-writes all halve vs 4-wave blocks.
// Prefetch loads are issued AFTER __syncthreads so the barrier's forced
// vmcnt-drain has nothing in flight; loads overlap the MFMA section.
__launch_bounds__(512, 2)
__global__ void gru_fused(const float* __restrict__ emb,
                          const float* __restrict__ W_ir,
                          const float* __restrict__ W_iz,
                          const float* __restrict__ b_ir,
                          const float* __restrict__ b_iz,
                          const int* __restrict__ walk,
                          unsigned short* __restrict__ hnb) {
  __shared__ unsigned short As[2][80 * 64];   // 2 x 10 KB, XOR-swizzled granules
  __shared__ unsigned short hout[8][4][8];    // per-wave hn bounce (packed store)

  const int tid = threadIdx.x;
  const int w = tid >> 6, lane = tid & 63;
  const int r = lane & 15, q = lane >> 4;
  const int c0 = blockIdx.x * 64;

  // ---- persistent B fragments: 2 tiles x 16 k-steps x 8 bf16 = 128 VGPRs ----
  const int pp = r & 3;                       // panel: 0=r0,1=z0,2=r1,3=z1
  const int chbase = c0 + 8 * w + (r >> 2);
  bf16x8 barr[2][16];
  float bias[2];
  #pragma unroll
  for (int t = 0; t < 2; ++t) {
    const int cch = chbase + 4 * t;
    const float* wrow = ((pp & 1) ? W_iz : W_ir)
                      + (long)(pp >> 1) * H * H + (long)cch * H;
    #pragma unroll
    for (int ks = 0; ks < 16; ++ks) {
      const float* s = wrow + ks * 32 + q * 8;
      barr[t][ks] = cvt8(*(const float4*)s, *(const float4*)(s + 4));
    }
    bias[t] = ((pp & 1) ? b_iz : b_ir)[(pp >> 1) * H + cch];
  }

  // ---- A staging roles: thread -> row tid>>3 (0..63); tid<128 also 64..79 ---
  const int row0 = tid >> 3, g0 = tid & 7;
  const int row2 = 64 + row0;
  const bool has2 = (tid < 128);
  #define LMAP(m) (20 * (((m) >> 2) & 3) + 4 * ((m) >> 4) + ((m) & 3))
  #define SWZ(m)  ((m) * 64 + ((g0 ^ ((m) & 7)) * 8))
  const int L0 = LMAP(row0), L2 = LMAP(row2);
  const int sw0 = SWZ(row0), sw2 = SWZ(row2);

  const int sb = blockIdx.y;
  const int ngA = (2500 * sb) >> 7;
  const int ngB = (2500 * (sb + 1)) >> 7;

  int v0 = walk[ngA * 80 + L0]; v0 = ((unsigned)v0 < VV) ? v0 : 0;
  int cur0 = v0 * H, cur2 = 0;
  if (has2) { int v2 = walk[ngA * 80 + L2]; v2 = ((unsigned)v2 < VV) ? v2 : 0; cur2 = v2 * H; }

  float4 pa0, pb0, pa2 = {0,0,0,0}, pb2 = {0,0,0,0};
  {                                           // prologue: prefetch chunk 0
    const float* s0 = emb + cur0 + g0 * 8;
    pa0 = *(const float4*)s0; pb0 = *(const float4*)(s0 + 4);
    if (has2) { const float* s2 = emb + cur2 + g0 * 8;
                pa2 = *(const float4*)s2; pb2 = *(const float4*)(s2 + 4); }
  }

  f32x4 acc[5][2];
  const f32x4 fz = {0.f, 0.f, 0.f, 0.f};

  for (int ng = ngA; ng < ngB; ++ng) {
    #pragma unroll
    for (int mt = 0; mt < 5; ++mt)
      #pragma unroll
      for (int t = 0; t < 2; ++t) acc[mt][t] = fz;

    const int ngn = (ng + 1 < ngB) ? ng + 1 : ng;   // clamped walk prefetch
    int n0 = walk[ngn * 80 + L0]; n0 = ((unsigned)n0 < VV) ? n0 : 0;
    const int nxt0 = n0 * H;
    int nxt2 = 0;
    if (has2) { int n2 = walk[ngn * 80 + L2]; n2 = ((unsigned)n2 < VV) ? n2 : 0; nxt2 = n2 * H; }

    #pragma unroll
    for (int kc = 0; kc < 8; ++kc) {
      unsigned short* Ab = &As[kc & 1][0];
      // consume prefetched chunk kc -> LDS
      cvt_store8(&Ab[sw0], pa0, pb0);
      if (has2) cvt_store8(&Ab[sw2], pa2, pb2);
      __syncthreads();
      // issue prefetch for chunk kc+1 AFTER the barrier (nothing in flight
      // at the drain; loads overlap the MFMA section below)
      {
        const int ko = (kc < 7) ? (kc + 1) * 64 : 0;
        const int o0 = (kc < 7) ? cur0 : nxt0;
        const int o2 = (kc < 7) ? cur2 : nxt2;
        const float* s0 = emb + o0 + ko + g0 * 8;
        pa0 = *(const float4*)s0; pb0 = *(const float4*)(s0 + 4);
        if (has2) { const float* s2 = emb + o2 + ko + g0 * 8;
                    pa2 = *(const float4*)s2; pb2 = *(const float4*)(s2 + 4); }
      }
      #pragma unroll
      for (int ks = 0; ks < 2; ++ks) {
        bf16x8 a[5];
        #pragma unroll
        for (int mt = 0; mt < 5; ++mt) {
          const int ar = mt * 16 + r;
          a[mt] = *(const bf16x8*)&Ab[ar * 64 + (((ks * 4 + q) ^ (ar & 7)) * 8)];
        }
        #pragma unroll
        for (int mt = 0; mt < 5; ++mt)
          #pragma unroll
          for (int t = 0; t < 2; ++t)
            acc[mt][t] = __builtin_amdgcn_mfma_f32_16x16x32_bf16(
                a[mt], barr[t][kc * 2 + ks], acc[mt][t], 0, 0, 0);
      }
    }

    // ---- epilogue: lane-local scan per N-tile; lane (q,r) = node q ----
    #pragma unroll
    for (int t = 0; t < 2; ++t) {
      float hn1 = 0.f, a2 = 1.f, b2 = 0.f;
      #pragma unroll
      for (int s = 0; s < 20; ++s) {
        const float y = acc[s >> 2][t][s & 3] + bias[t];
        const float tt = __shfl_xor(y, 1);
        const float z = sigm(tt);
        hn1 += z * (y - hn1);        // layer-1 direct scan (valid on p0 lanes)
        a2 *= (1.f - z);             // layer-2 affine (valid on p2 lanes)
        b2 += z * (y - b2);
      }
      const float u = __shfl_xor(hn1, 2);     // p2 gets p0's hn1
      if (pp == 2) hout[w][q][(r >> 2) + 4 * t] = f2bf(a2 * u + b2);
    }
    // packed store: 4 lanes/wave each write 16B (one node x 8 channels)
    if (lane < 4) {
      int4 v = *(const int4*)&hout[w][lane][0];
      *(int4*)(hnb + (long)(ng * 4 + lane) * 1024 + c0 + 8 * w) = v;
    }

    cur0 = nxt0; cur2 = nxt2;
  }
}

// ------- score slot (raw sigmoid) = sigmoid(hn . lin_w + lin_b) -------------
__global__ void score_kernel(const unsigned short* __restrict__ hnb,
                             const float* __restrict__ lin_w,
                             const float* __restrict__ lin_b,
                             float* __restrict__ R) {
  int tid = threadIdx.x;
  int wv = tid >> 6, lane = tid & 63;
  int node = blockIdx.x * 4 + wv;
  int k = lane * 8;
  int4 hv = *(const int4*)(hnb + (long)node * 1024 + k);
  float4 w0 = *(const float4*)(lin_w + k);
  float4 w1 = *(const float4*)(lin_w + k + 4);
  float s = bflo(hv.x) * w0.x + bfhi(hv.x) * w0.y + bflo(hv.y) * w0.z + bfhi(hv.y) * w0.w
          + bflo(hv.z) * w1.x + bfhi(hv.z) * w1.y + bflo(hv.w) * w1.z + bfhi(hv.w) * w1.w;
  #pragma unroll
  for (int off = 32; off > 0; off >>= 1) s += __shfl_down(s, off);
  if (lane == 0) R[256 + (long)node * 512] = sigm(s + lin_b[0]);
}

// ---------------- pred[e] = score[src] * score[dst] -------------------------
__global__ void pred_kernel(const int* __restrict__ eli, const float* __restrict__ R,
                            float* __restrict__ out) {
  int e = blockIdx.x * 256 + threadIdx.x;
  if (e < EE) {
    int a = eli[e];       a = (unsigned)a < NN ? a : 0;
    int b = eli[EE + e];  b = (unsigned)b < NN ? b : 0;
    out[e] = R[256 + (long)a * 512] * R[256 + (long)b * 512];
  }
}

// ---------------- out2 = hn @ skip_w.T + skip_b (in-place-safe MFMA) --------
// Block owns 32 rows (halves skip_w re-reads vs 16-row blocks).
__launch_bounds__(256)
__global__ void out2_kernel(const unsigned short* __restrict__ hnb,
                            const float* __restrict__ skip_w,
                            const float* __restrict__ skip_b,
                            float* __restrict__ out2) {
  __shared__ unsigned short Asl[32][520];
  __shared__ unsigned short Bsl[512][40];
  const int tid = threadIdx.x;
  const int lane = tid & 63, wv = tid >> 6;
  const int r = lane & 15, q = lane >> 4;
  const int m0 = blockIdx.x * 32;

  {
    int arow = tid >> 4;
    int acol = (tid & 15) * 32;
    #pragma unroll
    for (int hh = 0; hh < 2; ++hh) {
      int grow = m0 + hh * 16 + arow;
      unsigned short* dst = &Asl[hh * 16 + arow][acol];
      if (grow < NN) {
        const unsigned short* hr = hnb + (long)grow * 1024 + acol;
        *(int4*)(dst)      = *(const int4*)(hr);
        *(int4*)(dst + 8)  = *(const int4*)(hr + 8);
        *(int4*)(dst + 16) = *(const int4*)(hr + 16);
        *(int4*)(dst + 24) = *(const int4*)(hr + 24);
      } else {
        int4 z = {0, 0, 0, 0};
        *(int4*)(dst) = z; *(int4*)(dst + 8) = z;
        *(int4*)(dst + 16) = z; *(int4*)(dst + 24) = z;
      }
    }
  }

  const f32x4 fzero = {0.f, 0.f, 0.f, 0.f};
  f32x4 acc[2][8];
  #pragma unroll
  for (int rg = 0; rg < 2; ++rg)
    #pragma unroll
    for (int i = 0; i < 8; ++i) acc[rg][i] = fzero;

  const int ksub = (tid & 3) * 8;
  const int jb = tid >> 2;

  for (int k0 = 0; k0 < H; k0 += 32) {
    __syncthreads();
    #pragma unroll
    for (int it = 0; it < 8; ++it) {
      int jj = it * 64 + jb;
      const float* src = skip_w + (long)jj * H + k0 + ksub;
      cvt_store8(&Bsl[jj][ksub], *(const float4*)src, *(const float4*)(src + 4));
    }
    __syncthreads();
    bf16x8 af0 = *(const bf16x8*)&Asl[r][k0 + q * 8];
    bf16x8 af1 = *(const bf16x8*)&Asl[16 + r][k0 + q * 8];
    #pragma unroll
    for (int i = 0; i < 8; ++i) {
      bf16x8 bf = *(const bf16x8*)&Bsl[(wv * 8 + i) * 16 + r][q * 8];
      acc[0][i] = __builtin_amdgcn_mfma_f32_16x16x32_bf16(af0, bf, acc[0][i], 0, 0, 0);
      acc[1][i] = __builtin_amdgcn_mfma_f32_16x16x32_bf16(af1, bf, acc[1][i], 0, 0, 0);
    }
  }
  #pragma unroll
  for (int rg = 0; rg < 2; ++rg)
    #pragma unroll
    for (int i = 0; i < 8; ++i) {
      int col = (wv * 8 + i) * 16 + r;
      float sbv = skip_b[col];
      #pragma unroll
      for (int g = 0; g < 4; ++g) {
        int grow = m0 + rg * 16 + q * 4 + g;
        if (grow < NN) out2[(long)grow * H + col] = acc[rg][i][g] + sbv;
      }
    }
}

// ---------------- host launcher (d_ws intentionally unused) -----------------
extern "C" void kernel_launch(void* const* d_in, const int* in_sizes, int n_in,
                              void* d_out, int out_size, void* d_ws, size_t ws_size,
                              hipStream_t stream) {
  const float* emb    = (const float*)d_in[0];
  const float* W_ir   = (const float*)d_in[1];
  const float* b_ir   = (const float*)d_in[2];
  const float* W_iz   = (const float*)d_in[3];
  const float* b_iz   = (const float*)d_in[4];
  const float* lin_w  = (const float*)d_in[5];
  const float* lin_b  = (const float*)d_in[6];
  const float* skip_w = (const float*)d_in[7];
  const float* skip_b = (const float*)d_in[8];
  const int*   walk   = (const int*)d_in[9];
  const int*   eli    = (const int*)d_in[10];
  float* out = (float*)d_out;
  float* R   = out + EE;                           // out2 region: NN x H f32
  unsigned short* hnb = (unsigned short*)R;        // bf16 hn inside out2 slots

  dim3 g1(8, 128);
  gru_fused<<<g1, 512, 0, stream>>>(emb, W_ir, W_iz, b_ir, b_iz, walk, hnb);
  score_kernel<<<2500, 256, 0, stream>>>(hnb, lin_w, lin_b, R);
  pred_kernel<<<391, 256, 0, stream>>>(eli, R, out);        // before out2 (slots reused)
  out2_kernel<<<313, 256, 0, stream>>>(hnb, skip_w, skip_b, R);
}

// Round 9
// 783.616 us; speedup vs baseline: 1.1747x; 1.1747x over previous
//
#include <hip/hip_runtime.h>

#define H  512
#define NN 10000
#define SS 20
#define VV 100000
#define EE 100000

typedef __bf16 bf16x8 __attribute__((ext_vector_type(8)));
typedef float  f32x4  __attribute__((ext_vector_type(4)));

__device__ __forceinline__ unsigned short f2bf(float f) {
  unsigned u = __builtin_bit_cast(unsigned, f);
  u += 0x7FFFu + ((u >> 16) & 1u);
  return (unsigned short)(u >> 16);
}
__device__ __forceinline__ float bflo(int x) {
  return __builtin_bit_cast(float, (unsigned)x << 16);
}
__device__ __forceinline__ float bfhi(int x) {
  return __builtin_bit_cast(float, (unsigned)x & 0xFFFF0000u);
}
__device__ __forceinline__ float sigm(float x) { return 1.f / (1.f + __expf(-x)); }

// pack two f32 -> two bf16 in one dword: round-half-up (+0x8000) + v_perm_b32.
__device__ __forceinline__ unsigned pk(float lo, float hi) {
  unsigned a = __builtin_bit_cast(unsigned, lo) + 0x8000u;
  unsigned b = __builtin_bit_cast(unsigned, hi) + 0x8000u;
  return __builtin_amdgcn_perm(b, a, 0x07060302u);
}
__device__ __forceinline__ void cvt_store8(unsigned short* dst, float4 a, float4 b) {
  int4 v;
  v.x = (int)pk(a.x, a.y); v.y = (int)pk(a.z, a.w);
  v.z = (int)pk(b.x, b.y); v.w = (int)pk(b.z, b.w);
  *(int4*)dst = v;
}
__device__ __forceinline__ bf16x8 cvt8(float4 a, float4 b) {
  int4 v;
  v.x = (int)pk(a.x, a.y); v.y = (int)pk(a.z, a.w);
  v.z = (int)pk(b.x, b.y); v.w = (int)pk(b.z, b.w);
  return __builtin_bit_cast(bf16x8, v);
}

// ---------------- fused gather + GEMM + GRU scan (persistent-B) -------------
// grid (16 cgroups of 32 ch, 64 node-splits), block 256 = 4 waves.
// Wave w owns 32 cols as 2 N-tiles where tile 0 = h-panel (W_ir) and tile 1 =
// z-panel (W_iz) of the SAME (layer, channel): within a tile, col r ->
// layer ly=r&1, channel cch=c0+8w+(r>>1). So each lane's accumulators hold
// the (h, z) preact pair for its (node, layer, channel) -> the GRU scan is
// PURE lane-local VALU (no shuffle in the 20-step loop); one shfl_xor(1) at
// the end composes layer-2 from layer-1 (adjacent lanes = two layers).
// B (full K=512) persists in 128 VGPRs/lane, converted once per block.
// A-tile (80 rows x 64 k) double-buffered in LDS, XOR-swizzled (0 conflicts,
// r4-r6 verified). Prefetch loads are issued AFTER __syncthreads so the
// barrier's vmcnt-drain is empty and loads overlap the MFMA section.
// A rows PERMUTED: LDS row m=16mt+4q+g holds (node q, step 4mt+g).
__launch_bounds__(256, 2)
__global__ void gru_fused(const float* __restrict__ emb,
                          const float* __restrict__ W_ir,
                          const float* __restrict__ W_iz,
                          const float* __restrict__ b_ir,
                          const float* __restrict__ b_iz,
                          const int* __restrict__ walk,
                          unsigned short* __restrict__ hnb) {
  __shared__ unsigned short As[2][80 * 64];   // 2 x 10 KB, XOR-swizzled granules
  __shared__ unsigned short hout[2][4][32];   // [ng&1][node][channel-local]

  const int tid = threadIdx.x;
  const int w = tid >> 6, lane = tid & 63;
  const int r = lane & 15, q = lane >> 4;
  const int c0 = blockIdx.x * 32;

  // ---- persistent B fragments: 2 tiles x 16 k-steps x 8 bf16 = 128 VGPRs ---
  const int ly = r & 1;                       // layer of this lane's columns
  const int cch = c0 + 8 * w + (r >> 1);      // channel of this lane's columns
  bf16x8 barr[2][16];
  float bias2[2];
  #pragma unroll
  for (int t = 0; t < 2; ++t) {               // t: 0 = h (W_ir), 1 = z (W_iz)
    const float* wrow = (t ? W_iz : W_ir) + (long)ly * H * H + (long)cch * H;
    #pragma unroll
    for (int u = 0; u < 16; ++u) {
      const float* s = wrow + u * 32 + q * 8;
      barr[t][u] = cvt8(*(const float4*)s, *(const float4*)(s + 4));
    }
    bias2[t] = (t ? b_iz : b_ir)[ly * H + cch];
  }

  // ---- A staging roles: thread -> rows {tid>>3, +32, +64 (if tid<128)} -----
  const int row0 = tid >> 3, g0 = tid & 7;
  const int row1 = row0 + 32, row2 = row0 + 64;
  const bool has2 = (tid < 128);
  #define LMAP(m) (20 * (((m) >> 2) & 3) + 4 * ((m) >> 4) + ((m) & 3))
  #define SWZ(m)  ((m) * 64 + ((g0 ^ ((m) & 7)) * 8))
  const int L0 = LMAP(row0), L1 = LMAP(row1), L2 = LMAP(row2);
  const int sw0 = SWZ(row0), sw1 = SWZ(row1), sw2 = SWZ(row2);

  const int sb = blockIdx.y;
  const int ngA = (2500 * sb) >> 6;
  const int ngB = (2500 * (sb + 1)) >> 6;

  int v0 = walk[ngA * 80 + L0]; v0 = ((unsigned)v0 < VV) ? v0 : 0;
  int v1 = walk[ngA * 80 + L1]; v1 = ((unsigned)v1 < VV) ? v1 : 0;
  int cur0 = v0 * H, cur1 = v1 * H, cur2 = 0;
  if (has2) { int v2 = walk[ngA * 80 + L2]; v2 = ((unsigned)v2 < VV) ? v2 : 0; cur2 = v2 * H; }

  float4 pa0, pb0, pa1, pb1, pa2 = {0,0,0,0}, pb2 = {0,0,0,0};
  {                                           // prologue: prefetch chunk 0
    const float* s0 = emb + cur0 + g0 * 8;
    pa0 = *(const float4*)s0; pb0 = *(const float4*)(s0 + 4);
    const float* s1 = emb + cur1 + g0 * 8;
    pa1 = *(const float4*)s1; pb1 = *(const float4*)(s1 + 4);
    if (has2) { const float* s2 = emb + cur2 + g0 * 8;
                pa2 = *(const float4*)s2; pb2 = *(const float4*)(s2 + 4); }
  }

  f32x4 acc[5][2];
  const f32x4 fz = {0.f, 0.f, 0.f, 0.f};

  for (int ng = ngA; ng < ngB; ++ng) {
    #pragma unroll
    for (int mt = 0; mt < 5; ++mt)
      #pragma unroll
      for (int t = 0; t < 2; ++t) acc[mt][t] = fz;

    const int ngn = (ng + 1 < ngB) ? ng + 1 : ng;   // clamped walk prefetch
    int n0 = walk[ngn * 80 + L0]; n0 = ((unsigned)n0 < VV) ? n0 : 0;
    int n1 = walk[ngn * 80 + L1]; n1 = ((unsigned)n1 < VV) ? n1 : 0;
    const int nxt0 = n0 * H, nxt1 = n1 * H;
    int nxt2 = 0;
    if (has2) { int n2 = walk[ngn * 80 + L2]; n2 = ((unsigned)n2 < VV) ? n2 : 0; nxt2 = n2 * H; }

    #pragma unroll
    for (int kc = 0; kc < 8; ++kc) {
      unsigned short* Ab = &As[kc & 1][0];
      // consume prefetched chunk kc -> LDS
      cvt_store8(&Ab[sw0], pa0, pb0);
      cvt_store8(&Ab[sw1], pa1, pb1);
      if (has2) cvt_store8(&Ab[sw2], pa2, pb2);
      __syncthreads();
      // prefetch chunk kc+1 (or next ng's chunk 0) AFTER the barrier:
      // nothing in flight at the drain; loads overlap the MFMA section.
      {
        const int ko = (kc < 7) ? (kc + 1) * 64 : 0;
        const int o0 = (kc < 7) ? cur0 : nxt0;
        const int o1 = (kc < 7) ? cur1 : nxt1;
        const int o2 = (kc < 7) ? cur2 : nxt2;
        const float* s0 = emb + o0 + ko + g0 * 8;
        pa0 = *(const float4*)s0; pb0 = *(const float4*)(s0 + 4);
        const float* s1 = emb + o1 + ko + g0 * 8;
        pa1 = *(const float4*)s1; pb1 = *(const float4*)(s1 + 4);
        if (has2) { const float* s2 = emb + o2 + ko + g0 * 8;
                    pa2 = *(const float4*)s2; pb2 = *(const float4*)(s2 + 4); }
      }
      #pragma unroll
      for (int ks = 0; ks < 2; ++ks) {
        bf16x8 a[5];
        #pragma unroll
        for (int mt = 0; mt < 5; ++mt) {
          const int ar = mt * 16 + r;
          a[mt] = *(const bf16x8*)&Ab[ar * 64 + (((ks * 4 + q) ^ (ar & 7)) * 8)];
        }
        #pragma unroll
        for (int mt = 0; mt < 5; ++mt)
          #pragma unroll
          for (int t = 0; t < 2; ++t)
            acc[mt][t] = __builtin_amdgcn_mfma_f32_16x16x32_bf16(
                a[mt], barr[t][kc * 2 + ks], acc[mt][t], 0, 0, 0);
      }
    }

    // ---- epilogue: pure lane-local scan (h and z live in the same lane) ----
    {
      float hn1 = 0.f, a2 = 1.f, b2 = 0.f;
      #pragma unroll
      for (int s = 0; s < 20; ++s) {
        const float yh = acc[s >> 2][0][s & 3] + bias2[0];
        const float yz = acc[s >> 2][1][s & 3] + bias2[1];
        const float z = sigm(yz);
        hn1 += z * (yh - hn1);     // layer-1 direct scan (valid on ly==0 lanes)
        a2 *= (1.f - z);           // layer-2 affine (valid on ly==1 lanes)
        b2 += z * (yh - b2);
      }
      const float u2 = __shfl_xor(hn1, 1);    // ly1 lane gets ly0's hn1
      if (ly == 1) hout[ng & 1][q][8 * w + (r >> 1)] = f2bf(a2 * u2 + b2);
    }
    __syncthreads();
    // packed store: 16 threads write 4 nodes x 64B (4 x dwordx4, same line)
    if (tid < 16) {
      const int nd = tid >> 2, seg = tid & 3;
      int4 v = *(const int4*)&hout[ng & 1][nd][seg * 8];
      *(int4*)(hnb + (long)(ng * 4 + nd) * 1024 + c0 + seg * 8) = v;
    }
    cur0 = nxt0; cur1 = nxt1; cur2 = nxt2;
  }
}

// ------- score slot (raw sigmoid) = sigmoid(hn . lin_w + lin_b) -------------
__global__ void score_kernel(const unsigned short* __restrict__ hnb,
                             const float* __restrict__ lin_w,
                             const float* __restrict__ lin_b,
                             float* __restrict__ R) {
  int tid = threadIdx.x;
  int wv = tid >> 6, lane = tid & 63;
  int node = blockIdx.x * 4 + wv;
  int k = lane * 8;
  int4 hv = *(const int4*)(hnb + (long)node * 1024 + k);
  float4 w0 = *(const float4*)(lin_w + k);
  float4 w1 = *(const float4*)(lin_w + k + 4);
  float s = bflo(hv.x) * w0.x + bfhi(hv.x) * w0.y + bflo(hv.y) * w0.z + bfhi(hv.y) * w0.w
          + bflo(hv.z) * w1.x + bfhi(hv.z) * w1.y + bflo(hv.w) * w1.z + bfhi(hv.w) * w1.w;
  #pragma unroll
  for (int off = 32; off > 0; off >>= 1) s += __shfl_down(s, off);
  if (lane == 0) R[256 + (long)node * 512] = sigm(s + lin_b[0]);
}

// ---------------- pred[e] = score[src] * score[dst] -------------------------
__global__ void pred_kernel(const int* __restrict__ eli, const float* __restrict__ R,
                            float* __restrict__ out) {
  int e = blockIdx.x * 256 + threadIdx.x;
  if (e < EE) {
    int a = eli[e];       a = (unsigned)a < NN ? a : 0;
    int b = eli[EE + e];  b = (unsigned)b < NN ? b : 0;
    out[e] = R[256 + (long)a * 512] * R[256 + (long)b * 512];
  }
}

// ---------------- out2 = hn @ skip_w.T + skip_b (in-place-safe MFMA) --------
__launch_bounds__(256)
__global__ void out2_kernel(const unsigned short* __restrict__ hnb,
                            const float* __restrict__ skip_w,
                            const float* __restrict__ skip_b,
                            float* __restrict__ out2) {
  __shared__ unsigned short Asl[32][520];
  __shared__ unsigned short Bsl[512][40];
  const int tid = threadIdx.x;
  const int lane = tid & 63, wv = tid >> 6;
  const int r = lane & 15, q = lane >> 4;
  const int m0 = blockIdx.x * 32;

  {
    int arow = tid >> 4;
    int acol = (tid & 15) * 32;
    #pragma unroll
    for (int hh = 0; hh < 2; ++hh) {
      int grow = m0 + hh * 16 + arow;
      unsigned short* dst = &Asl[hh * 16 + arow][acol];
      if (grow < NN) {
        const unsigned short* hr = hnb + (long)grow * 1024 + acol;
        *(int4*)(dst)      = *(const int4*)(hr);
        *(int4*)(dst + 8)  = *(const int4*)(hr + 8);
        *(int4*)(dst + 16) = *(const int4*)(hr + 16);
        *(int4*)(dst + 24) = *(const int4*)(hr + 24);
      } else {
        int4 z = {0, 0, 0, 0};
        *(int4*)(dst) = z; *(int4*)(dst + 8) = z;
        *(int4*)(dst + 16) = z; *(int4*)(dst + 24) = z;
      }
    }
  }

  const f32x4 fzero = {0.f, 0.f, 0.f, 0.f};
  f32x4 acc[2][8];
  #pragma unroll
  for (int rg = 0; rg < 2; ++rg)
    #pragma unroll
    for (int i = 0; i < 8; ++i) acc[rg][i] = fzero;

  const int ksub = (tid & 3) * 8;
  const int jb = tid >> 2;

  for (int k0 = 0; k0 < H; k0 += 32) {
    __syncthreads();
    #pragma unroll
    for (int it = 0; it < 8; ++it) {
      int jj = it * 64 + jb;
      const float* src = skip_w + (long)jj * H + k0 + ksub;
      cvt_store8(&Bsl[jj][ksub], *(const float4*)src, *(const float4*)(src + 4));
    }
    __syncthreads();
    bf16x8 af0 = *(const bf16x8*)&Asl[r][k0 + q * 8];
    bf16x8 af1 = *(const bf16x8*)&Asl[16 + r][k0 + q * 8];
    #pragma unroll
    for (int i = 0; i < 8; ++i) {
      bf16x8 bf = *(const bf16x8*)&Bsl[(wv * 8 + i) * 16 + r][q * 8];
      acc[0][i] = __builtin_amdgcn_mfma_f32_16x16x32_bf16(af0, bf, acc[0][i], 0, 0, 0);
      acc[1][i] = __builtin_amdgcn_mfma_f32_16x16x32_bf16(af1, bf, acc[1][i], 0, 0, 0);
    }
  }
  #pragma unroll
  for (int rg = 0; rg < 2; ++rg)
    #pragma unroll
    for (int i = 0; i < 8; ++i) {
      int col = (wv * 8 + i) * 16 + r;
      float sbv = skip_b[col];
      #pragma unroll
      for (int g = 0; g < 4; ++g) {
        int grow = m0 + rg * 16 + q * 4 + g;
        if (grow < NN) out2[(long)grow * H + col] = acc[rg][i][g] + sbv;
      }
    }
}

// ---------------- host launcher (d_ws is UNUSABLE in this harness) ----------
extern "C" void kernel_launch(void* const* d_in, const int* in_sizes, int n_in,
                              void* d_out, int out_size, void* d_ws, size_t ws_size,
                              hipStream_t stream) {
  const float* emb    = (const float*)d_in[0];
  const float* W_ir   = (const float*)d_in[1];
  const float* b_ir   = (const float*)d_in[2];
  const float* W_iz   = (const float*)d_in[3];
  const float* b_iz   = (const float*)d_in[4];
  const float* lin_w  = (const float*)d_in[5];
  const float* lin_b  = (const float*)d_in[6];
  const float* skip_w = (const float*)d_in[7];
  const float* skip_b = (const float*)d_in[8];
  const int*   walk   = (const int*)d_in[9];
  const int*   eli    = (const int*)d_in[10];
  float* out = (float*)d_out;
  float* R   = out + EE;                           // out2 region: NN x H f32
  unsigned short* hnb = (unsigned short*)R;        // bf16 hn inside out2 slots

  dim3 g1(16, 64);
  gru_fused<<<g1, 256, 0, stream>>>(emb, W_ir, W_iz, b_ir, b_iz, walk, hnb);
  score_kernel<<<2500, 256, 0, stream>>>(hnb, lin_w, lin_b, R);
  pred_kernel<<<391, 256, 0, stream>>>(eli, R, out);        // before out2 (slots reused)
  out2_kernel<<<313, 256, 0, stream>>>(hnb, skip_w, skip_b, R);
}